// Round 1
// baseline (34.210 us; speedup 1.0000x reference)
//
#include <hip/hip_runtime.h>
#include <math.h>

// ---------------- complex helpers (device) ----------------
struct cplx { float re, im; };
__device__ __forceinline__ cplx cmul(cplx a, cplx b) {
    return { a.re * b.re - a.im * b.im, a.re * b.im + a.im * b.re };
}
__device__ __forceinline__ cplx cadd(cplx a, cplx b) { return { a.re + b.re, a.im + b.im }; }

__device__ void zero4(cplx C[4][4]) {
    for (int i = 0; i < 4; ++i)
        for (int j = 0; j < 4; ++j) C[i][j] = { 0.f, 0.f };
}
__device__ void mm4(const cplx A[4][4], const cplx B[4][4], cplx C[4][4]) {
    for (int i = 0; i < 4; ++i)
        for (int j = 0; j < 4; ++j) {
            cplx acc = { 0.f, 0.f };
            for (int k = 0; k < 4; ++k) acc = cadd(acc, cmul(A[i][k], B[k][j]));
            C[i][j] = acc;
        }
}
// kron(A,B)[2a+b][2c+d] = A[a][c] * B[b][d]
__device__ void kron2(const cplx A[2][2], const cplx B[2][2], cplx C[4][4]) {
    for (int a = 0; a < 2; ++a)
        for (int b = 0; b < 2; ++b)
            for (int c = 0; c < 2; ++c)
                for (int d = 0; d < 2; ++d)
                    C[2 * a + b][2 * c + d] = cmul(A[a][c], B[b][d]);
}

// ---------------- prologue: build M0, M1 (32 floats) from weights ----------------
// weights flat: w[0]=w00 (RX), w[1]=w01 (RY), w[2]=w10 (RZ), w[3]=w11 (RX)
__global__ void build_M(const float* __restrict__ w, float* __restrict__ M) {
    if (threadIdx.x != 0 || blockIdx.x != 0) return;

    cplx rx0[2][2], ry[2][2], rz[2][2], rx1[2][2];
    {
        float t = 0.5f * w[0], c = cosf(t), s = sinf(t);
        rx0[0][0] = { c, 0 }; rx0[0][1] = { 0, -s };
        rx0[1][0] = { 0, -s }; rx0[1][1] = { c, 0 };
    }
    {
        float t = 0.5f * w[1], c = cosf(t), s = sinf(t);
        ry[0][0] = { c, 0 }; ry[0][1] = { -s, 0 };
        ry[1][0] = { s, 0 }; ry[1][1] = { c, 0 };
    }
    {
        float t = 0.5f * w[2], c = cosf(t), s = sinf(t);
        rz[0][0] = { c, -s }; rz[0][1] = { 0, 0 };
        rz[1][0] = { 0, 0 };  rz[1][1] = { c, s };
    }
    {
        float t = 0.5f * w[3], c = cosf(t), s = sinf(t);
        rx1[0][0] = { c, 0 }; rx1[0][1] = { 0, -s };
        rx1[1][0] = { 0, -s }; rx1[1][1] = { c, 0 };
    }
    cplx I2[2][2] = { { {1,0},{0,0} }, { {0,0},{1,0} } };

    cplx g1[4][4], g2[4][4], g5[4][4], g6[4][4];
    kron2(I2, rx0, g1);   // kron(I, RX(w00))
    kron2(ry, I2, g2);    // kron(RY(w01), I)
    kron2(I2, rz, g5);    // kron(I, RZ(w10))
    kron2(rx1, I2, g6);   // kron(RX(w11), I)

    cplx g3[4][4]; zero4(g3);   // CNOT10
    g3[0][0] = { 1, 0 }; g3[1][3] = { 1, 0 }; g3[2][2] = { 1, 0 }; g3[3][1] = { 1, 0 };
    cplx g4[4][4]; zero4(g4);   // CNOT01
    g4[0][0] = { 1, 0 }; g4[1][1] = { 1, 0 }; g4[2][3] = { 1, 0 }; g4[3][2] = { 1, 0 };

    cplx T1[4][4], T2[4][4], T3[4][4], T4[4][4], U[4][4];
    mm4(g2, g1, T1);
    mm4(g3, T1, T2);
    mm4(g4, T2, T3);
    mm4(g5, T3, T4);
    mm4(g6, T4, U);

    const float sg0[4] = { 1.f, 1.f, -1.f, -1.f };
    const float sg1[4] = { 1.f, -1.f, 1.f, -1.f };
    for (int j = 0; j < 4; ++j)
        for (int k = 0; k < 4; ++k) {
            float m0 = 0.f, m1 = 0.f;
            for (int i = 0; i < 4; ++i) {
                float dot = U[i][j].re * U[i][k].re + U[i][j].im * U[i][k].im;
                m0 += sg0[i] * dot;
                m1 += sg1[i] * dot;
            }
            M[j * 4 + k] = m0;
            M[16 + j * 4 + k] = m1;
        }
}

// ---------------- main kernel: one thread per output pixel ----------------
// x: (B,128,128) f32.  out: (B,64,64,2) f32 viewed as float2.
__global__ __launch_bounds__(256) void qconv_main(const float* __restrict__ x,
                                                  const float* __restrict__ M,
                                                  float2* __restrict__ out,
                                                  int total) {
    int t = blockIdx.x * 256 + threadIdx.x;
    if (t >= total) return;
    int q = t & 63;
    int p = (t >> 6) & 63;
    int b = t >> 12;

    int r = 2 * p + 1; if (r > 126) r = 126;
    int c = 2 * q + 1; if (c > 126) c = 126;

    const float* row = x + ((size_t)(b * 128 + r)) * 128;
    float phi0 = row[c];
    float phi1 = row[c + 1];

    const float HALF_PI = 1.57079632679489662f;
    float s0, c0, s1, c1;
    __sincosf(HALF_PI * phi0, &s0, &c0);
    __sincosf(HALF_PI * phi1, &s1, &c1);

    float v[4] = { c0 * c1, c0 * s1, s0 * c1, s0 * s1 };

    float z0 = 0.f, z1 = 0.f;
#pragma unroll
    for (int j = 0; j < 4; ++j) {
#pragma unroll
        for (int k = 0; k < 4; ++k) {
            float pp = v[j] * v[k];
            z0 = fmaf(M[j * 4 + k], pp, z0);
            z1 = fmaf(M[16 + j * 4 + k], pp, z1);
        }
    }
    out[t] = make_float2(z0, z1);
}

extern "C" void kernel_launch(void* const* d_in, const int* in_sizes, int n_in,
                              void* d_out, int out_size, void* d_ws, size_t ws_size,
                              hipStream_t stream) {
    const float* x = (const float*)d_in[0];
    const float* w = (const float*)d_in[1];
    float* M = (float*)d_ws;            // 32 floats
    float2* out = (float2*)d_out;

    int B = in_sizes[0] / (128 * 128);
    int total = B * 64 * 64;            // one thread per (b,p,q) pixel

    build_M<<<1, 64, 0, stream>>>(w, M);
    qconv_main<<<(total + 255) / 256, 256, 0, stream>>>(x, M, out, total);
}

// Round 2
// 27.590 us; speedup vs baseline: 1.2399x; 1.2399x over previous
//
#include <hip/hip_runtime.h>
#include <math.h>

// ---------------- complex helpers (device) ----------------
struct cplx { float re, im; };
__device__ __forceinline__ cplx cmul(cplx a, cplx b) {
    return { a.re * b.re - a.im * b.im, a.re * b.im + a.im * b.re };
}
__device__ __forceinline__ cplx cadd(cplx a, cplx b) { return { a.re + b.re, a.im + b.im }; }

__device__ void zero4(cplx C[4][4]) {
    for (int i = 0; i < 4; ++i)
        for (int j = 0; j < 4; ++j) C[i][j] = { 0.f, 0.f };
}
__device__ void mm4(const cplx A[4][4], const cplx B[4][4], cplx C[4][4]) {
    for (int i = 0; i < 4; ++i)
        for (int j = 0; j < 4; ++j) {
            cplx acc = { 0.f, 0.f };
            for (int k = 0; k < 4; ++k) acc = cadd(acc, cmul(A[i][k], B[k][j]));
            C[i][j] = acc;
        }
}
// kron(A,B)[2a+b][2c+d] = A[a][c] * B[b][d]
__device__ void kron2(const cplx A[2][2], const cplx B[2][2], cplx C[4][4]) {
    for (int a = 0; a < 2; ++a)
        for (int b = 0; b < 2; ++b)
            for (int c = 0; c < 2; ++c)
                for (int d = 0; d < 2; ++d)
                    C[2 * a + b][2 * c + d] = cmul(A[a][c], B[b][d]);
}

// ---------------- prologue: build A0,A1 (2x 3x3 = 18 floats) from weights ----
// z_k(pixel) = t0^T A_k t1,  t = (1, cos(pi*phi), sin(pi*phi))
// weights flat: w[0]=w00 (RX), w[1]=w01 (RY), w[2]=w10 (RZ), w[3]=w11 (RX)
__global__ void build_A(const float* __restrict__ w, float* __restrict__ Aout) {
    if (threadIdx.x != 0 || blockIdx.x != 0) return;

    cplx rx0[2][2], ry[2][2], rz[2][2], rx1[2][2];
    {
        float t = 0.5f * w[0], c = cosf(t), s = sinf(t);
        rx0[0][0] = { c, 0 }; rx0[0][1] = { 0, -s };
        rx0[1][0] = { 0, -s }; rx0[1][1] = { c, 0 };
    }
    {
        float t = 0.5f * w[1], c = cosf(t), s = sinf(t);
        ry[0][0] = { c, 0 }; ry[0][1] = { -s, 0 };
        ry[1][0] = { s, 0 }; ry[1][1] = { c, 0 };
    }
    {
        float t = 0.5f * w[2], c = cosf(t), s = sinf(t);
        rz[0][0] = { c, -s }; rz[0][1] = { 0, 0 };
        rz[1][0] = { 0, 0 };  rz[1][1] = { c, s };
    }
    {
        float t = 0.5f * w[3], c = cosf(t), s = sinf(t);
        rx1[0][0] = { c, 0 }; rx1[0][1] = { 0, -s };
        rx1[1][0] = { 0, -s }; rx1[1][1] = { c, 0 };
    }
    cplx I2[2][2] = { { {1,0},{0,0} }, { {0,0},{1,0} } };

    cplx g1[4][4], g2[4][4], g5[4][4], g6[4][4];
    kron2(I2, rx0, g1);   // kron(I, RX(w00))
    kron2(ry, I2, g2);    // kron(RY(w01), I)
    kron2(I2, rz, g5);    // kron(I, RZ(w10))
    kron2(rx1, I2, g6);   // kron(RX(w11), I)

    cplx g3[4][4]; zero4(g3);   // CNOT10
    g3[0][0] = { 1, 0 }; g3[1][3] = { 1, 0 }; g3[2][2] = { 1, 0 }; g3[3][1] = { 1, 0 };
    cplx g4[4][4]; zero4(g4);   // CNOT01
    g4[0][0] = { 1, 0 }; g4[1][1] = { 1, 0 }; g4[2][3] = { 1, 0 }; g4[3][2] = { 1, 0 };

    cplx T1[4][4], T2[4][4], T3[4][4], T4[4][4], U[4][4];
    mm4(g2, g1, T1);
    mm4(g3, T1, T2);
    mm4(g4, T2, T3);
    mm4(g5, T3, T4);
    mm4(g6, T4, U);

    // M_k[j][l] = sum_i sign_k[i] * (ReU[i][j]ReU[i][l] + ImU[i][j]ImU[i][l])
    const float sg0[4] = { 1.f, 1.f, -1.f, -1.f };
    const float sg1[4] = { 1.f, -1.f, 1.f, -1.f };
    float M0[4][4], M1[4][4];
    for (int j = 0; j < 4; ++j)
        for (int l = 0; l < 4; ++l) {
            float m0 = 0.f, m1 = 0.f;
            for (int i = 0; i < 4; ++i) {
                float dot = U[i][j].re * U[i][l].re + U[i][j].im * U[i][l].im;
                m0 += sg0[i] * dot;
                m1 += sg1[i] * dot;
            }
            M0[j][l] = m0;
            M1[j][l] = m1;
        }

    // Pair->trig-basis transform: (u_j u_k) = T[j][k] . (1, C, S)
    // u0^2=(1+C)/2, u0u1=S/2, u1^2=(1-C)/2
    float T[2][2][3];
    T[0][0][0] = 0.5f; T[0][0][1] = 0.5f;  T[0][0][2] = 0.f;
    T[0][1][0] = 0.f;  T[0][1][1] = 0.f;   T[0][1][2] = 0.5f;
    T[1][0][0] = 0.f;  T[1][0][1] = 0.f;   T[1][0][2] = 0.5f;
    T[1][1][0] = 0.5f; T[1][1][1] = -0.5f; T[1][1][2] = 0.f;

    // A_m[a][b] = sum_{j0,k0,j1,k1} M_m[2j0+j1][2k0+k1] T[j0][k0][a] T[j1][k1][b]
    for (int a = 0; a < 3; ++a)
        for (int b = 0; b < 3; ++b) {
            float a0 = 0.f, a1 = 0.f;
            for (int j0 = 0; j0 < 2; ++j0)
                for (int k0 = 0; k0 < 2; ++k0)
                    for (int j1 = 0; j1 < 2; ++j1)
                        for (int k1 = 0; k1 < 2; ++k1) {
                            float tt = T[j0][k0][a] * T[j1][k1][b];
                            a0 += M0[2 * j0 + j1][2 * k0 + k1] * tt;
                            a1 += M1[2 * j0 + j1][2 * k0 + k1] * tt;
                        }
            Aout[a * 3 + b] = a0;
            Aout[9 + a * 3 + b] = a1;
        }
}

// ---------------- main kernel: 2 pixels per thread ----------------
// x: (B,128,128) f32.  out: (B,64,64,2) f32 -> one float4 per thread.
__device__ __forceinline__ float readlane_f(float v, int lane) {
    int i = __builtin_amdgcn_readlane(__float_as_int(v), lane);
    return __int_as_float(i);
}

__device__ __forceinline__ float2 qpix(float phi0, float phi1, const float a[18], int base) {
    const float PI_F = 3.14159265358979f;
    float s0, c0, s1, c1;
    __sincosf(PI_F * phi0, &s0, &c0);
    __sincosf(PI_F * phi1, &s1, &c1);
    float z0, z1;
    {
        float w0 = fmaf(a[base + 2], s1, fmaf(a[base + 1], c1, a[base + 0]));
        float w1 = fmaf(a[base + 5], s1, fmaf(a[base + 4], c1, a[base + 3]));
        float w2 = fmaf(a[base + 8], s1, fmaf(a[base + 7], c1, a[base + 6]));
        z0 = fmaf(s0, w2, fmaf(c0, w1, w0));
    }
    {
        float w0 = fmaf(a[base + 11], s1, fmaf(a[base + 10], c1, a[base + 9]));
        float w1 = fmaf(a[base + 14], s1, fmaf(a[base + 13], c1, a[base + 12]));
        float w2 = fmaf(a[base + 17], s1, fmaf(a[base + 16], c1, a[base + 15]));
        z1 = fmaf(s0, w2, fmaf(c0, w1, w0));
    }
    return make_float2(z0, z1);
}

__global__ __launch_bounds__(256) void qconv_main(const float* __restrict__ x,
                                                  const float* __restrict__ Abuf,
                                                  float4* __restrict__ out,
                                                  int total) {
    int t = blockIdx.x * 256 + threadIdx.x;
    int lane = threadIdx.x & 63;

    // Hoist the 18 coefficients into SGPRs: 1 VMEM per wave + 18 readlane.
    float mv = 0.f;
    if (lane < 18) mv = Abuf[lane];
    float a[18];
#pragma unroll
    for (int i = 0; i < 18; ++i) a[i] = readlane_f(mv, i);

    if (t >= total) return;

    int lp = t & 31;            // half-row index: pixels q=2lp, 2lp+1
    int p = (t >> 5) & 63;
    int b = t >> 11;

    int r = 2 * p + 1; if (r > 126) r = 126;

    const float4* row4 = (const float4*)(x + ((size_t)(b * 128 + r)) * 128);
    float4 v = row4[lp];                       // elems 4lp .. 4lp+3
    float nx = __shfl_down(v.x, 1);            // neighbor's elem 4lp+4

    // pixel q=2lp:   c=4lp+1 -> (v.y, v.z)
    float2 o0 = qpix(v.y, v.z, a, 0);
    // pixel q=2lp+1: c=4lp+3 -> (v.w, nx);  lp==31: c clamps to 126 -> (v.z, v.w)
    float p0 = (lp == 31) ? v.z : v.w;
    float p1 = (lp == 31) ? v.w : nx;
    float2 o1 = qpix(p0, p1, a, 0);

    out[t] = make_float4(o0.x, o0.y, o1.x, o1.y);
}

extern "C" void kernel_launch(void* const* d_in, const int* in_sizes, int n_in,
                              void* d_out, int out_size, void* d_ws, size_t ws_size,
                              hipStream_t stream) {
    const float* x = (const float*)d_in[0];
    const float* w = (const float*)d_in[1];
    float* A = (float*)d_ws;            // 18 floats
    float4* out = (float4*)d_out;

    int B = in_sizes[0] / (128 * 128);
    int total = B * 64 * 32;            // one thread per 2 horizontal pixels

    build_A<<<1, 64, 0, stream>>>(w, A);
    qconv_main<<<(total + 255) / 256, 256, 0, stream>>>(x, A, out, total);
}

// Round 3
// 22.911 us; speedup vs baseline: 1.4932x; 1.2042x over previous
//
#include <hip/hip_runtime.h>
#include <math.h>

// ============ prologue: build A0,A1 (2x 3x3 = 18 floats) from weights ============
// z_k(pixel) = t0^T A_k t1,  t = (1, cos(pi*phi), sin(pi*phi))
// Gate order: U = g6 g5 g4 g3 g2 g1, applied right-to-left to basis columns.
// g1=I(x)RX(w0)  g2=RY(w1)(x)I  g3=CNOT10  g4=CNOT01  g5=I(x)RZ(w2)  g6=RX(w3)(x)I

__device__ __forceinline__ void rx_pair(float& ur, float& ui, float& vr, float& vi,
                                        float cc, float ss) {
    // RX = [[c, -i s],[-i s, c]]
    float nur = fmaf(cc, ur,  ss * vi);
    float nui = fmaf(cc, ui, -ss * vr);
    float nvr = fmaf(cc, vr,  ss * ui);
    float nvi = fmaf(cc, vi, -ss * ur);
    ur = nur; ui = nui; vr = nvr; vi = nvi;
}
__device__ __forceinline__ void ry_pair(float& ur, float& ui, float& vr, float& vi,
                                        float cc, float ss) {
    // RY = [[c, -s],[s, c]] (real)
    float nur = fmaf(cc, ur, -ss * vr);
    float nui = fmaf(cc, ui, -ss * vi);
    float nvr = fmaf(cc, vr,  ss * ur);
    float nvi = fmaf(cc, vi,  ss * ui);
    ur = nur; ui = nui; vr = nvr; vi = nvi;
}
__device__ __forceinline__ void rz_diag(float& ur, float& ui, float& vr, float& vi,
                                        float cc, float ss) {
    // u *= exp(-i t/2) = c - i s ;  v *= exp(+i t/2) = c + i s
    float nur = fmaf(cc, ur,  ss * ui);
    float nui = fmaf(cc, ui, -ss * ur);
    float nvr = fmaf(cc, vr, -ss * vi);
    float nvi = fmaf(cc, vi,  ss * vr);
    ur = nur; ui = nui; vr = nvr; vi = nvi;
}

__global__ void build_A(const float* __restrict__ w, float* __restrict__ Aout) {
    float s[4], c[4];
#pragma unroll
    for (int i = 0; i < 4; ++i) __sincosf(0.5f * w[i], &s[i], &c[i]);

    float Ur[4][4], Ui[4][4];   // [row i][col j]
#pragma unroll
    for (int j = 0; j < 4; ++j) {
        float vr0 = (j == 0), vr1 = (j == 1), vr2 = (j == 2), vr3 = (j == 3);
        float vi0 = 0, vi1 = 0, vi2 = 0, vi3 = 0;
        // g1: RX(w0) on low bit -> pairs (0,1),(2,3)
        rx_pair(vr0, vi0, vr1, vi1, c[0], s[0]);
        rx_pair(vr2, vi2, vr3, vi3, c[0], s[0]);
        // g2: RY(w1) on high bit -> pairs (0,2),(1,3)
        ry_pair(vr0, vi0, vr2, vi2, c[1], s[1]);
        ry_pair(vr1, vi1, vr3, vi3, c[1], s[1]);
        // g3: CNOT10 -> swap entries 1,3
        { float tr = vr1, ti = vi1; vr1 = vr3; vi1 = vi3; vr3 = tr; vi3 = ti; }
        // g4: CNOT01 -> swap entries 2,3
        { float tr = vr2, ti = vi2; vr2 = vr3; vi2 = vi3; vr3 = tr; vi3 = ti; }
        // g5: RZ(w2) on low bit -> (0,1) and (2,3) diagonal phases
        rz_diag(vr0, vi0, vr1, vi1, c[2], s[2]);
        rz_diag(vr2, vi2, vr3, vi3, c[2], s[2]);
        // g6: RX(w3) on high bit -> pairs (0,2),(1,3)
        rx_pair(vr0, vi0, vr2, vi2, c[3], s[3]);
        rx_pair(vr1, vi1, vr3, vi3, c[3], s[3]);
        Ur[0][j] = vr0; Ui[0][j] = vi0;
        Ur[1][j] = vr1; Ui[1][j] = vi1;
        Ur[2][j] = vr2; Ui[2][j] = vi2;
        Ur[3][j] = vr3; Ui[3][j] = vi3;
    }

    // M_k[j][l] = sum_i sg_k[i] * (ReU[i][j]ReU[i][l] + ImU[i][j]ImU[i][l])
    const float sg0[4] = { 1.f, 1.f, -1.f, -1.f };
    const float sg1[4] = { 1.f, -1.f, 1.f, -1.f };
    float M0[4][4], M1[4][4];
#pragma unroll
    for (int j = 0; j < 4; ++j)
#pragma unroll
        for (int l = 0; l < 4; ++l) {
            float m0 = 0.f, m1 = 0.f;
#pragma unroll
            for (int i = 0; i < 4; ++i) {
                float dot = Ur[i][j] * Ur[i][l] + Ui[i][j] * Ui[i][l];
                m0 += sg0[i] * dot;
                m1 += sg1[i] * dot;
            }
            M0[j][l] = m0;
            M1[j][l] = m1;
        }

    // Pair->trig basis: u0^2=(1+C)/2, u0u1=u1u0=S/2, u1^2=(1-C)/2
    float T[2][2][3];
    T[0][0][0] = 0.5f; T[0][0][1] = 0.5f;  T[0][0][2] = 0.f;
    T[0][1][0] = 0.f;  T[0][1][1] = 0.f;   T[0][1][2] = 0.5f;
    T[1][0][0] = 0.f;  T[1][0][1] = 0.f;   T[1][0][2] = 0.5f;
    T[1][1][0] = 0.5f; T[1][1][1] = -0.5f; T[1][1][2] = 0.f;

    if (threadIdx.x == 0 && blockIdx.x == 0) {
#pragma unroll
        for (int a = 0; a < 3; ++a)
#pragma unroll
            for (int b = 0; b < 3; ++b) {
                float a0 = 0.f, a1 = 0.f;
#pragma unroll
                for (int j0 = 0; j0 < 2; ++j0)
#pragma unroll
                    for (int k0 = 0; k0 < 2; ++k0)
#pragma unroll
                        for (int j1 = 0; j1 < 2; ++j1)
#pragma unroll
                            for (int k1 = 0; k1 < 2; ++k1) {
                                float tt = T[j0][k0][a] * T[j1][k1][b];
                                a0 += M0[2 * j0 + j1][2 * k0 + k1] * tt;
                                a1 += M1[2 * j0 + j1][2 * k0 + k1] * tt;
                            }
                Aout[a * 3 + b] = a0;
                Aout[9 + a * 3 + b] = a1;
            }
    }
}

// ============ main kernel: 4 pixels per thread ============
__device__ __forceinline__ float readlane_f(float v, int lane) {
    int i = __builtin_amdgcn_readlane(__float_as_int(v), lane);
    return __int_as_float(i);
}

__device__ __forceinline__ float2 qpix(float phi0, float phi1, const float a[18]) {
    const float PI_F = 3.14159265358979f;
    float s0, c0, s1, c1;
    __sincosf(PI_F * phi0, &s0, &c0);
    __sincosf(PI_F * phi1, &s1, &c1);
    float w0 = fmaf(a[2], s1, fmaf(a[1], c1, a[0]));
    float w1 = fmaf(a[5], s1, fmaf(a[4], c1, a[3]));
    float w2 = fmaf(a[8], s1, fmaf(a[7], c1, a[6]));
    float z0 = fmaf(s0, w2, fmaf(c0, w1, w0));
    float u0 = fmaf(a[11], s1, fmaf(a[10], c1, a[9]));
    float u1 = fmaf(a[14], s1, fmaf(a[13], c1, a[12]));
    float u2 = fmaf(a[17], s1, fmaf(a[16], c1, a[15]));
    float z1 = fmaf(s0, u2, fmaf(c0, u1, u0));
    return make_float2(z0, z1);
}

// x: (B,128,128) f32.  Thread t covers pixels q=4lp..4lp+3 of row p, image b.
__global__ __launch_bounds__(256) void qconv_main(const float* __restrict__ x,
                                                  const float* __restrict__ Abuf,
                                                  float4* __restrict__ out,
                                                  int total) {
    int t = blockIdx.x * 256 + threadIdx.x;
    int lane = threadIdx.x & 63;

    // 18 coefficients -> SGPRs: 1 VMEM per wave + 18 readlane.
    float mv = 0.f;
    if (lane < 18) mv = Abuf[lane];
    float a[18];
#pragma unroll
    for (int i = 0; i < 18; ++i) a[i] = readlane_f(mv, i);

    if (t >= total) return;

    int lp = t & 15;           // 16 threads per row (4 pixels each)
    int p  = (t >> 4) & 63;
    int b  = t >> 10;

    int r = 2 * p + 1; if (r > 126) r = 126;
    const float4* row4 = (const float4*)(x + ((size_t)(b * 128 + r)) * 128);
    float4 v1 = row4[2 * lp];          // elems 8lp .. 8lp+3
    float4 v2 = row4[2 * lp + 1];      // elems 8lp+4 .. 8lp+7
    float nx = __shfl_down(v1.x, 1);   // elem 8lp+8 (next lane, same wave; unused at lp==15)

    float2 o0 = qpix(v1.y, v1.z, a);                 // q=4lp:   c=8lp+1
    float2 o1 = qpix(v1.w, v2.x, a);                 // q=4lp+1: c=8lp+3
    float2 o2 = qpix(v2.y, v2.z, a);                 // q=4lp+2: c=8lp+5
    float e7 = (lp == 15) ? v2.z : v2.w;             // q=4lp+3: c=8lp+7, clamp->126 at lp==15
    float e8 = (lp == 15) ? v2.w : nx;
    float2 o3 = qpix(e7, e8, a);

    out[2 * t]     = make_float4(o0.x, o0.y, o1.x, o1.y);
    out[2 * t + 1] = make_float4(o2.x, o2.y, o3.x, o3.y);
}

extern "C" void kernel_launch(void* const* d_in, const int* in_sizes, int n_in,
                              void* d_out, int out_size, void* d_ws, size_t ws_size,
                              hipStream_t stream) {
    const float* x = (const float*)d_in[0];
    const float* w = (const float*)d_in[1];
    float* A = (float*)d_ws;            // 18 floats
    float4* out = (float4*)d_out;

    int B = in_sizes[0] / (128 * 128);
    int total = B * 64 * 16;            // one thread per 4 horizontal pixels

    build_A<<<1, 64, 0, stream>>>(w, A);
    qconv_main<<<(total + 255) / 256, 256, 0, stream>>>(x, A, out, total);
}

// Round 4
// 17.525 us; speedup vs baseline: 1.9521x; 1.3074x over previous
//
#include <hip/hip_runtime.h>
#include <math.h>

// Closed form (Heisenberg-picture Pauli propagation through the 6-gate circuit):
//   z1 = cos(b + pi*phi0)
//   z0 = cos(a+d) * cos(pi*phi1) * z1
// where a=w[0,0] (RX low), b=w[0,1] (RY high), d=w[1,1] (RX high).
// w[1,0] (RZ) provably does not affect Z-expectations.
//
// x: (B,128,128) f32; out: (B,64,64,2) f32.
// Pixel (p,q): row r=min(2p+1,126), phi0=x[r,c], phi1=x[r,c+1], c=min(2q+1,126).
// Thread t handles 4 pixels q=4lp..4lp+3 via two float4 row loads + 1 shuffle.

__global__ __launch_bounds__(256) void qconv_main(const float* __restrict__ x,
                                                  const float* __restrict__ w,
                                                  float4* __restrict__ out,
                                                  int total) {
    int t = blockIdx.x * 256 + threadIdx.x;
    if (t >= total) return;

    // Uniform weight prologue (scalar loads + 2 fast cos per thread).
    float wa = w[0], wb = w[1], wd = w[3];
    float R = __cosf(wa + wd);

    int lp  = t & 15;            // 16 threads per row, 4 pixels each
    int p   = (t >> 4) & 63;
    int img = t >> 10;

    int r = 2 * p + 1; if (r > 126) r = 126;
    const float4* row4 = (const float4*)(x + ((size_t)(img * 128 + r)) * 128);
    float4 v1 = row4[2 * lp];          // elems 8lp .. 8lp+3
    float4 v2 = row4[2 * lp + 1];      // elems 8lp+4 .. 8lp+7
    float nx = __shfl_down(v1.x, 1);   // elem 8lp+8 from next lane (unused at lp==15)

    const float PI_F = 3.14159265358979f;

    // pixel 0: c=8lp+1 -> (v1.y, v1.z)
    float z1_0 = __cosf(fmaf(PI_F, v1.y, wb));
    float z0_0 = R * __cosf(PI_F * v1.z) * z1_0;
    // pixel 1: c=8lp+3 -> (v1.w, v2.x)
    float z1_1 = __cosf(fmaf(PI_F, v1.w, wb));
    float z0_1 = R * __cosf(PI_F * v2.x) * z1_1;
    // pixel 2: c=8lp+5 -> (v2.y, v2.z)
    float z1_2 = __cosf(fmaf(PI_F, v2.y, wb));
    float z0_2 = R * __cosf(PI_F * v2.z) * z1_2;
    // pixel 3: c=8lp+7 -> (v2.w, nx); q=63 clamps c->126 -> (v2.z, v2.w)
    float e7 = (lp == 15) ? v2.z : v2.w;
    float e8 = (lp == 15) ? v2.w : nx;
    float z1_3 = __cosf(fmaf(PI_F, e7, wb));
    float z0_3 = R * __cosf(PI_F * e8) * z1_3;

    out[2 * t]     = make_float4(z0_0, z1_0, z0_1, z1_1);
    out[2 * t + 1] = make_float4(z0_2, z1_2, z0_3, z1_3);
}

extern "C" void kernel_launch(void* const* d_in, const int* in_sizes, int n_in,
                              void* d_out, int out_size, void* d_ws, size_t ws_size,
                              hipStream_t stream) {
    const float* x = (const float*)d_in[0];
    const float* w = (const float*)d_in[1];
    float4* out = (float4*)d_out;

    int B = in_sizes[0] / (128 * 128);
    int total = B * 64 * 16;            // one thread per 4 horizontal pixels

    qconv_main<<<(total + 255) / 256, 256, 0, stream>>>(x, w, out, total);
}

// Round 6
// 14.998 us; speedup vs baseline: 2.2809x; 1.1685x over previous
//
#include <hip/hip_runtime.h>
#include <math.h>

// Closed form (Heisenberg-picture Pauli propagation through the 6-gate circuit):
//   z1 = cos(b + pi*phi0)
//   z0 = cos(a+d) * cos(pi*phi1) * z1
// where a=w[0,0] (RX low), b=w[0,1] (RY high), d=w[1,1] (RX high).
// w[1,0] (RZ) provably does not affect Z-expectations.
//
// x: (B,128,128) f32; out: (B,64,64,2) f32.
// Pixel (p,q): r=min(2p+1,126), c=min(2q+1,126), phi0=x[r,c], phi1=x[r,c+1].
//
// Wave-dense mapping: lanes 0-31 cover one odd row (512 B) contiguously,
// lanes 32-63 the next; every load/store instruction is fully dense.
// Thread = 2 pixels: one float4 load, one float4 store, one shuffle.

typedef float vfloat4 __attribute__((ext_vector_type(4)));

__global__ __launch_bounds__(256) void qconv_main(const float* __restrict__ x,
                                                  const float* __restrict__ w,
                                                  vfloat4* __restrict__ out,
                                                  int total) {
    int t = blockIdx.x * 256 + threadIdx.x;
    if (t >= total) return;

    float wb = w[1];
    float R  = __cosf(w[0] + w[3]);

    int l   = t & 31;            // 32 threads per row, 2 pixels each
    int rid = t >> 5;            // global row id: img*64 + p
    int p   = rid & 63;
    int img = rid >> 6;

    int r = 2 * p + 1; if (r > 126) r = 126;
    const vfloat4* row4 = (const vfloat4*)(x + ((size_t)(img * 128 + r)) * 128);
    vfloat4 v = row4[l];               // elements 4l .. 4l+3 (dense across 32 lanes)
    float nx = __shfl_down(v.x, 1);    // element 4l+4 (lane l+1); unused at l==31

    const float PI_F = 3.14159265358979f;

    // pixel q=2l:   c=4l+1 -> (v.y, v.z)
    float z1_0 = __cosf(fmaf(PI_F, v.y, wb));
    float z0_0 = R * __cosf(PI_F * v.z) * z1_0;
    // pixel q=2l+1: c=4l+3 -> (v.w, nx); l==31: c=127 clamps to 126 -> (v.z, v.w)
    float e0 = (l == 31) ? v.z : v.w;
    float e1 = (l == 31) ? v.w : nx;
    float z1_1 = __cosf(fmaf(PI_F, e0, wb));
    float z0_1 = R * __cosf(PI_F * e1) * z1_1;

    vfloat4 o = { z0_0, z1_0, z0_1, z1_1 };
    __builtin_nontemporal_store(o, &out[t]);
}

extern "C" void kernel_launch(void* const* d_in, const int* in_sizes, int n_in,
                              void* d_out, int out_size, void* d_ws, size_t ws_size,
                              hipStream_t stream) {
    const float* x = (const float*)d_in[0];
    const float* w = (const float*)d_in[1];
    vfloat4* out = (vfloat4*)d_out;

    int B = in_sizes[0] / (128 * 128);
    int total = B * 64 * 32;            // one thread per 2 horizontal pixels

    qconv_main<<<(total + 255) / 256, 256, 0, stream>>>(x, w, out, total);
}

// Round 7
// 13.997 us; speedup vs baseline: 2.4441x; 1.0715x over previous
//
#include <hip/hip_runtime.h>
#include <math.h>

// Closed form (Heisenberg-picture Pauli propagation through the 6-gate circuit):
//   z1 = cos(b + pi*phi0)
//   z0 = cos(a+d) * cos(pi*phi1) * z1
// where a=w[0,0] (RX low), b=w[0,1] (RY high), d=w[1,1] (RX high).
// w[1,0] (RZ) provably does not affect Z-expectations.
//
// x: (B,128,128) f32; out: (B,64,64,2) f32.
// Pixel (p,q): r=min(2p+1,126), c=min(2q+1,126), phi0=x[r,c], phi1=x[r,c+1].
//
// Wave-dense, ILP=2 mapping: each wave covers 4 output rows via two
// independent fully-dense 1 KB loads (lanes 0-31 = one odd row's 512 B,
// lanes 32-63 = the next row), both issued before compute, then two dense
// 1 KB nontemporal stores. Thread = 4 pixels: 2 loads, 2 shuffles, 2 stores.

typedef float vfloat4 __attribute__((ext_vector_type(4)));

__device__ __forceinline__ vfloat4 qpair(vfloat4 v, float nx, int l,
                                         float wb, float R) {
    const float PI_F = 3.14159265358979f;
    // pixel q=2l:   c=4l+1 -> (v.y, v.z)
    float z1_0 = __cosf(fmaf(PI_F, v.y, wb));
    float z0_0 = R * __cosf(PI_F * v.z) * z1_0;
    // pixel q=2l+1: c=4l+3 -> (v.w, nx); l==31: c=127 clamps to 126 -> (v.z, v.w)
    float e0 = (l == 31) ? v.z : v.w;
    float e1 = (l == 31) ? v.w : nx;
    float z1_1 = __cosf(fmaf(PI_F, e0, wb));
    float z0_1 = R * __cosf(PI_F * e1) * z1_1;
    vfloat4 o = { z0_0, z1_0, z0_1, z1_1 };
    return o;
}

__global__ __launch_bounds__(256) void qconv_main(const float* __restrict__ x,
                                                  const float* __restrict__ w,
                                                  vfloat4* __restrict__ out,
                                                  int nwaves) {
    int tid  = blockIdx.x * 256 + threadIdx.x;
    int wid  = tid >> 6;
    if (wid >= nwaves) return;
    int lane = threadIdx.x & 63;
    int l    = lane & 31;          // position within the row (float4 index)
    int half = lane >> 5;          // which of the wave's row-pair halves

    int h0 = wid * 4 + half;       // output rows h0 and h0+2 (h = img*64 + p)
    int h1 = h0 + 2;

    int p0 = h0 & 63, i0 = h0 >> 6;
    int p1 = h1 & 63, i1 = h1 >> 6;
    int r0 = 2 * p0 + 1; if (r0 > 126) r0 = 126;
    int r1 = 2 * p1 + 1; if (r1 > 126) r1 = 126;

    const vfloat4* rowA = (const vfloat4*)(x + ((size_t)(i0 * 128 + r0)) * 128);
    const vfloat4* rowB = (const vfloat4*)(x + ((size_t)(i1 * 128 + r1)) * 128);

    // Issue both loads before any dependent use (ILP=2).
    vfloat4 va = rowA[l];
    vfloat4 vb = rowB[l];

    float wb_ = w[1];
    float R   = __cosf(w[0] + w[3]);

    float nxa = __shfl_down(va.x, 1);   // elem 4l+4 (unused at l==31)
    float nxb = __shfl_down(vb.x, 1);

    vfloat4 oa = qpair(va, nxa, l, wb_, R);
    vfloat4 ob = qpair(vb, nxb, l, wb_, R);

    __builtin_nontemporal_store(oa, &out[h0 * 32 + l]);
    __builtin_nontemporal_store(ob, &out[h1 * 32 + l]);
}

extern "C" void kernel_launch(void* const* d_in, const int* in_sizes, int n_in,
                              void* d_out, int out_size, void* d_ws, size_t ws_size,
                              hipStream_t stream) {
    const float* x = (const float*)d_in[0];
    const float* w = (const float*)d_in[1];
    vfloat4* out = (vfloat4*)d_out;

    int B = in_sizes[0] / (128 * 128);
    int totalRows = B * 64;
    int nwaves = totalRows / 4;          // each wave covers 4 output rows
    int nthreads = nwaves * 64;

    qconv_main<<<(nthreads + 255) / 256, 256, 0, stream>>>(x, w, out, nwaves);
}

// Round 8
// 13.589 us; speedup vs baseline: 2.5174x; 1.0300x over previous
//
#include <hip/hip_runtime.h>
#include <math.h>

// Closed form (Heisenberg-picture Pauli propagation through the 6-gate circuit):
//   z1 = cos(b + pi*phi0)
//   z0 = cos(a+d) * cos(pi*phi1) * z1
// where a=w[0,0] (RX low), b=w[0,1] (RY high), d=w[1,1] (RX high).
// w[1,0] (RZ) provably does not affect Z-expectations.
//
// x: (B,128,128) f32; out: (B,64,64,2) f32.
// Pixel (p,q): r=min(2p+1,126), c=min(2q+1,126), phi0=x[r,c], phi1=x[r,c+1].
//
// Wave-dense, MLP=4 mapping: each wave covers 8 output rows via four
// independent fully-dense 1 KB loads (lanes 0-31 = one odd row's 512 B,
// lanes 32-63 = the next row), all issued before compute, then four dense
// 1 KB nontemporal stores. Thread = 8 pixels: 4 loads, 4 shuffles, 4 stores.

typedef float vfloat4 __attribute__((ext_vector_type(4)));

__device__ __forceinline__ vfloat4 qpair(vfloat4 v, float nx, int l,
                                         float wb, float R) {
    const float PI_F = 3.14159265358979f;
    // pixel q=2l:   c=4l+1 -> (v.y, v.z)
    float z1_0 = __cosf(fmaf(PI_F, v.y, wb));
    float z0_0 = R * __cosf(PI_F * v.z) * z1_0;
    // pixel q=2l+1: c=4l+3 -> (v.w, nx); l==31: c=127 clamps to 126 -> (v.z, v.w)
    float e0 = (l == 31) ? v.z : v.w;
    float e1 = (l == 31) ? v.w : nx;
    float z1_1 = __cosf(fmaf(PI_F, e0, wb));
    float z0_1 = R * __cosf(PI_F * e1) * z1_1;
    vfloat4 o = { z0_0, z1_0, z0_1, z1_1 };
    return o;
}

__global__ __launch_bounds__(256) void qconv_main(const float* __restrict__ x,
                                                  const float* __restrict__ w,
                                                  vfloat4* __restrict__ out,
                                                  int nwaves) {
    int tid  = blockIdx.x * 256 + threadIdx.x;
    int wid  = tid >> 6;
    if (wid >= nwaves) return;
    int lane = threadIdx.x & 63;
    int l    = lane & 31;          // float4 index within the 512 B row
    int half = lane >> 5;          // which row of each pair this half-wave covers

    // This wave's 8 output rows: h_k = wid*8 + 2k + half, k=0..3 (h = img*64 + p)
    int hbase = wid * 8 + half;

    const vfloat4* rows[4];
#pragma unroll
    for (int k = 0; k < 4; ++k) {
        int h = hbase + 2 * k;
        int p = h & 63, img = h >> 6;
        int r = 2 * p + 1; if (r > 126) r = 126;
        rows[k] = (const vfloat4*)(x + ((size_t)(img * 128 + r)) * 128);
    }

    // Issue all four loads before any dependent use (MLP=4).
    vfloat4 v0 = rows[0][l];
    vfloat4 v1 = rows[1][l];
    vfloat4 v2 = rows[2][l];
    vfloat4 v3 = rows[3][l];

    float wb_ = w[1];
    float R   = __cosf(w[0] + w[3]);

    float n0 = __shfl_down(v0.x, 1);   // elem 4l+4 (unused at l==31)
    float n1 = __shfl_down(v1.x, 1);
    float n2 = __shfl_down(v2.x, 1);
    float n3 = __shfl_down(v3.x, 1);

    vfloat4 o0 = qpair(v0, n0, l, wb_, R);
    vfloat4 o1 = qpair(v1, n1, l, wb_, R);
    vfloat4 o2 = qpair(v2, n2, l, wb_, R);
    vfloat4 o3 = qpair(v3, n3, l, wb_, R);

    __builtin_nontemporal_store(o0, &out[(hbase + 0) * 32 + l]);
    __builtin_nontemporal_store(o1, &out[(hbase + 2) * 32 + l]);
    __builtin_nontemporal_store(o2, &out[(hbase + 4) * 32 + l]);
    __builtin_nontemporal_store(o3, &out[(hbase + 6) * 32 + l]);
}

extern "C" void kernel_launch(void* const* d_in, const int* in_sizes, int n_in,
                              void* d_out, int out_size, void* d_ws, size_t ws_size,
                              hipStream_t stream) {
    const float* x = (const float*)d_in[0];
    const float* w = (const float*)d_in[1];
    vfloat4* out = (vfloat4*)d_out;

    int B = in_sizes[0] / (128 * 128);
    int totalRows = B * 64;
    int nwaves = totalRows / 8;          // each wave covers 8 output rows
    int nthreads = nwaves * 64;

    qconv_main<<<(nthreads + 255) / 256, 256, 0, stream>>>(x, w, out, nwaves);
}